// Round 5
// baseline (175.034 us; speedup 1.0000x reference)
//
#include <hip/hip_runtime.h>
#include <hip/hip_bf16.h>
#include <hip/hip_cooperative_groups.h>
#include <cstddef>

#define N_NODES 100000
#define HIDDEN  128
#define N_EDGES 1600000

typedef int   i32x4 __attribute__((ext_vector_type(4)));
typedef float f32x4 __attribute__((ext_vector_type(4)));

__device__ __forceinline__ float dot8(const f32x4 a0, const f32x4 a1,
                                      const f32x4 b0, const f32x4 b1) {
    return a0.x * b0.x + a0.y * b0.y + a0.z * b0.z + a0.w * b0.w
         + a1.x * b1.x + a1.y * b1.y + a1.z * b1.z + a1.w * b1.w;
}

// Fused: phase 1 computes per-node dots (wave = 16 rows), grid sync,
// phase 2 gathers + sigmoid (thread = 4 edges). Single dispatch.
// 1024 blocks x 256 thr, __launch_bounds__(256,4) -> 4 blocks/CU co-resident.
__global__ __launch_bounds__(256, 4) void fused_kernel(
        const int* __restrict__ ei,
        const float* __restrict__ x,
        const float* __restrict__ w,
        float* __restrict__ out,
        float* __restrict__ s_row,
        float* __restrict__ s_col) {
    const int lane = threadIdx.x & 63;
    const int sub  = lane & 15;           // position within row (16 lanes/row)
    const int rsub = lane >> 4;           // which of the 4 rows in a quad

    // ---- Phase 1: s_row[n] = x[n].w_r, s_col[n] = x[n].w_c ----
    {
        const f32x4 wr0 = *reinterpret_cast<const f32x4*>(w + 8 * sub);
        const f32x4 wr1 = *reinterpret_cast<const f32x4*>(w + 8 * sub + 4);
        const f32x4 wc0 = *reinterpret_cast<const f32x4*>(w + HIDDEN + 8 * sub);
        const f32x4 wc1 = *reinterpret_cast<const f32x4*>(w + HIDDEN + 8 * sub + 4);

        const int gwave  = (blockIdx.x * blockDim.x + threadIdx.x) >> 6;
        const int nwaves = (gridDim.x * blockDim.x) >> 6;   // 4096

        for (int u = gwave; u < N_NODES / 16; u += nwaves) {
            const int q0 = u * 4;         // 4 quads = 16 rows
            f32x4 v0[4], v1[4];
            #pragma unroll
            for (int k = 0; k < 4; ++k) {
                const float* xp =
                    x + ((size_t)(q0 + k) * 4 + rsub) * HIDDEN + 8 * sub;
                v0[k] = *reinterpret_cast<const f32x4*>(xp);
                v1[k] = *reinterpret_cast<const f32x4*>(xp + 4);
            }
            #pragma unroll
            for (int k = 0; k < 4; ++k) {
                float pr = dot8(v0[k], v1[k], wr0, wr1);
                float pc = dot8(v0[k], v1[k], wc0, wc1);
                #pragma unroll
                for (int off = 8; off > 0; off >>= 1) {
                    pr += __shfl_down(pr, off, 64);
                    pc += __shfl_down(pc, off, 64);
                }
                if (sub == 0) {
                    const int n = 4 * (q0 + k) + rsub;
                    s_row[n] = pr;
                    s_col[n] = pc;
                }
            }
        }
    }

    // ---- Grid-wide barrier (device-scope visibility of s tables) ----
    __threadfence();
    cooperative_groups::this_grid().sync();

    // ---- Phase 2: out[e] = sigmoid(s_row[row[e]] + s_col[col[e]]) ----
    {
        const int t0   = blockIdx.x * blockDim.x + threadIdx.x;
        const int nthr = gridDim.x * blockDim.x;             // 262144
        for (int t = t0; t < N_EDGES / 4; t += nthr) {
            const i32x4 r = __builtin_nontemporal_load(
                reinterpret_cast<const i32x4*>(ei + 4 * t));
            const i32x4 c = __builtin_nontemporal_load(
                reinterpret_cast<const i32x4*>(ei + N_EDGES + 4 * t));

            float z0 = s_row[r.x] + s_col[c.x];
            float z1 = s_row[r.y] + s_col[c.y];
            float z2 = s_row[r.z] + s_col[c.z];
            float z3 = s_row[r.w] + s_col[c.w];

            f32x4 o;
            o.x = 1.0f / (1.0f + __expf(-z0));
            o.y = 1.0f / (1.0f + __expf(-z1));
            o.z = 1.0f / (1.0f + __expf(-z2));
            o.w = 1.0f / (1.0f + __expf(-z3));
            __builtin_nontemporal_store(o, reinterpret_cast<f32x4*>(out + 4 * t));
        }
    }
}

extern "C" void kernel_launch(void* const* d_in, const int* in_sizes, int n_in,
                              void* d_out, int out_size, void* d_ws, size_t ws_size,
                              hipStream_t stream) {
    const int*   edge_index = (const int*)d_in[0];   // (2, N_EDGES) int32
    const float* x          = (const float*)d_in[1]; // (N_NODES, HIDDEN)
    const float* att_weight = (const float*)d_in[2]; // (1, 2*HIDDEN)
    float*       out        = (float*)d_out;         // (N_EDGES, 1)

    float* s_row = (float*)d_ws;           // N_NODES floats
    float* s_col = s_row + N_NODES;        // N_NODES floats

    void* args[] = {(void*)&edge_index, (void*)&x, (void*)&att_weight,
                    (void*)&out, (void*)&s_row, (void*)&s_col};
    hipLaunchCooperativeKernel((void*)fused_kernel, dim3(1024), dim3(256),
                               args, 0, stream);
}

// Round 6
// 132.042 us; speedup vs baseline: 1.3256x; 1.3256x over previous
//
#include <hip/hip_runtime.h>
#include <hip/hip_bf16.h>
#include <cstddef>
#include <cstdint>

#define N_NODES 100000
#define HIDDEN  128
#define N_EDGES 1600000
#define NBLK    1024
#define NTHR    256

typedef int   i32x4 __attribute__((ext_vector_type(4)));
typedef float f32x4 __attribute__((ext_vector_type(4)));

__device__ __forceinline__ float dot8(const f32x4 a0, const f32x4 a1,
                                      const f32x4 b0, const f32x4 b1) {
    return a0.x * b0.x + a0.y * b0.y + a0.z * b0.z + a0.w * b0.w
         + a1.x * b1.x + a1.y * b1.y + a1.z * b1.z + a1.w * b1.w;
}

// Single dispatch. Phase 1: per-node dots (wave = 16 rows/unit, grid-stride).
// s-stores are agent-scope relaxed atomics -> write-through to die-level
// coherence point (no dirty L2, no wbl2 storm). Lightweight grid barrier:
// one threadfence + relaxed agent atomicAdd per BLOCK (thread 0), spin on
// relaxed agent load. Edge indices prefetched into registers pre-barrier.
// 1024 blocks x 256 thr = half of residency capacity -> co-resident.
__global__ __launch_bounds__(256) void fused_kernel(
        const int* __restrict__ ei,
        const float* __restrict__ x,
        const float* __restrict__ w,
        float* __restrict__ out,
        float* __restrict__ s_row,
        float* __restrict__ s_col,
        unsigned* __restrict__ bar) {
    const int tid  = blockIdx.x * blockDim.x + threadIdx.x;
    const int lane = threadIdx.x & 63;
    const int sub  = lane & 15;           // position within row (16 lanes/row)
    const int rsub = lane >> 4;           // which of the 4 rows in a quad

    // ---- Phase 1: s_row[n] = x[n].w_r, s_col[n] = x[n].w_c ----
    {
        const f32x4 wr0 = *reinterpret_cast<const f32x4*>(w + 8 * sub);
        const f32x4 wr1 = *reinterpret_cast<const f32x4*>(w + 8 * sub + 4);
        const f32x4 wc0 = *reinterpret_cast<const f32x4*>(w + HIDDEN + 8 * sub);
        const f32x4 wc1 = *reinterpret_cast<const f32x4*>(w + HIDDEN + 8 * sub + 4);

        const int wv     = tid >> 6;                      // 0..4095
        const int nwaves = (NBLK * NTHR) >> 6;            // 4096

        for (int u = wv; u < N_NODES / 16; u += nwaves) {
            const int q0 = u * 4;                         // 4 quads = 16 rows
            f32x4 v0[4], v1[4];
            #pragma unroll
            for (int k = 0; k < 4; ++k) {
                const float* xp =
                    x + ((size_t)(q0 + k) * 4 + rsub) * HIDDEN + 8 * sub;
                v0[k] = __builtin_nontemporal_load(
                    reinterpret_cast<const f32x4*>(xp));
                v1[k] = __builtin_nontemporal_load(
                    reinterpret_cast<const f32x4*>(xp + 4));
            }
            #pragma unroll
            for (int k = 0; k < 4; ++k) {
                float pr = dot8(v0[k], v1[k], wr0, wr1);
                float pc = dot8(v0[k], v1[k], wc0, wc1);
                #pragma unroll
                for (int off = 8; off > 0; off >>= 1) {
                    pr += __shfl_down(pr, off, 64);
                    pc += __shfl_down(pc, off, 64);
                }
                if (sub == 0) {
                    const int n = 4 * (q0 + k) + rsub;
                    // agent-scope write-through: visible at die-level
                    // coherence point once retired (no L2 flush needed)
                    __hip_atomic_store(&s_row[n], pr, __ATOMIC_RELAXED,
                                       __HIP_MEMORY_SCOPE_AGENT);
                    __hip_atomic_store(&s_col[n], pc, __ATOMIC_RELAXED,
                                       __HIP_MEMORY_SCOPE_AGENT);
                }
            }
        }
    }

    // ---- Prefetch this thread's edge indices (independent of phase 1) ----
    const bool active = tid < N_EDGES / 8;   // 8 edges per thread
    i32x4 r0 = {}, r1 = {}, c0 = {}, c1 = {};
    if (active) {
        r0 = __builtin_nontemporal_load(
            reinterpret_cast<const i32x4*>(ei + 8 * tid));
        r1 = __builtin_nontemporal_load(
            reinterpret_cast<const i32x4*>(ei + 8 * tid + 4));
        c0 = __builtin_nontemporal_load(
            reinterpret_cast<const i32x4*>(ei + N_EDGES + 8 * tid));
        c1 = __builtin_nontemporal_load(
            reinterpret_cast<const i32x4*>(ei + N_EDGES + 8 * tid + 4));
    }

    // ---- Lightweight grid barrier ----
    __syncthreads();                 // retires all block stores (vmcnt 0)
    if (threadIdx.x == 0) {
        __threadfence();             // backstop; cheap: no dirty s-lines
        __hip_atomic_fetch_add(bar, 1u, __ATOMIC_RELAXED,
                               __HIP_MEMORY_SCOPE_AGENT);
        while (__hip_atomic_load(bar, __ATOMIC_RELAXED,
                                 __HIP_MEMORY_SCOPE_AGENT) < NBLK) {
            __builtin_amdgcn_s_sleep(2);
        }
    }
    __syncthreads();                 // block waits on thread 0's spin

    // ---- Phase 2: out[e] = sigmoid(s_row[row[e]] + s_col[col[e]]) ----
    if (active) {
        float z[8];
        z[0] = s_row[r0.x] + s_col[c0.x];
        z[1] = s_row[r0.y] + s_col[c0.y];
        z[2] = s_row[r0.z] + s_col[c0.z];
        z[3] = s_row[r0.w] + s_col[c0.w];
        z[4] = s_row[r1.x] + s_col[c1.x];
        z[5] = s_row[r1.y] + s_col[c1.y];
        z[6] = s_row[r1.z] + s_col[c1.z];
        z[7] = s_row[r1.w] + s_col[c1.w];

        f32x4 o0, o1;
        o0.x = 1.0f / (1.0f + __expf(-z[0]));
        o0.y = 1.0f / (1.0f + __expf(-z[1]));
        o0.z = 1.0f / (1.0f + __expf(-z[2]));
        o0.w = 1.0f / (1.0f + __expf(-z[3]));
        o1.x = 1.0f / (1.0f + __expf(-z[4]));
        o1.y = 1.0f / (1.0f + __expf(-z[5]));
        o1.z = 1.0f / (1.0f + __expf(-z[6]));
        o1.w = 1.0f / (1.0f + __expf(-z[7]));
        __builtin_nontemporal_store(o0, reinterpret_cast<f32x4*>(out + 8 * tid));
        __builtin_nontemporal_store(o1, reinterpret_cast<f32x4*>(out + 8 * tid + 4));
    }
}

extern "C" void kernel_launch(void* const* d_in, const int* in_sizes, int n_in,
                              void* d_out, int out_size, void* d_ws, size_t ws_size,
                              hipStream_t stream) {
    const int*   edge_index = (const int*)d_in[0];   // (2, N_EDGES) int32
    const float* x          = (const float*)d_in[1]; // (N_NODES, HIDDEN)
    const float* att_weight = (const float*)d_in[2]; // (1, 2*HIDDEN)
    float*       out        = (float*)d_out;         // (N_EDGES, 1)

    float*    s_row = (float*)d_ws;                  // N_NODES floats
    float*    s_col = s_row + N_NODES;               // N_NODES floats
    unsigned* bar   = (unsigned*)((char*)d_ws + (1u << 20)); // 1MB offset

    // zero the barrier counter each call (graph-capturable)
    hipMemsetAsync((void*)bar, 0, sizeof(unsigned), stream);

    fused_kernel<<<NBLK, NTHR, 0, stream>>>(
        edge_index, x, att_weight, out, s_row, s_col, bar);
}